// Round 7
// baseline (349.897 us; speedup 1.0000x reference)
//
#include <hip/hip_runtime.h>

// Fused 2-layer LSTM (H=64) + Dense(64,sigmoid) + Dense(1,sigmoid), MFMA bf16.
// Transposed-z formulation: z^T[gate-unit, batch] = Wt @ [x|h]^T.
// B=4096, T=256, F=32. One WG = 1024 threads = 16 waves handles BB=16 rows.
// Waves 0-7 (L1): layer 1 step u, 2 M-tiles each; waves 8-15 (L2): layer 2
// step u-1, 2 M-tiles each. One barrier per step; double-buffered h1/h2/x.
//
// ISSUE-BOUND + TAIL (R6-refined): VALU issue ~1000 cyc/SIMD-step, of which
// ~770 is transcendental (10 ex2 + 2 rcp per wave at ~16cyc wave64) --
// irreducible (5 nonlinearities/cell x 2 cells). Step is 1886 cyc: the
// ~700-cyc excess over issue is the exposed serial-chain tail of each
// barrier interval. R7 attacks the tail:
//  - SPLIT MFMA TREES: z = (A0 x + bias) || (A1 h0 + A2 h1) as two parallel
//    accumulators merged by v_pk_add_f32 -> dep depth 3-4 MFMA -> 2 + add.
//  - s_setprio(1) on the LDS+MFMA front phase, (0) on gate math: waves in
//    the front phase out-prioritize gate-phase waves, creating intra-
//    interval phase skew (trans bursts hide under other waves' MFMA/LDS).
// Everything else retained from R5/R6 (all verified): packed-f32 gate pair
// math, batched rcp, x2-unrolled static parity, lgkm-only barrier (no vmcnt
// drain), XOR-swizzled conflict-free h layout, b32 cvt_pk h-writes,
// activation scales folded into weights, bias via MFMA C operand.
// MFMA 16x16x32 layouts (learn_hip-verified):
//   A[m=lane&15][k=(lane>>4)*8+j], B[k=(lane>>4)*8+j][n=lane&15],
//   C/D: col=lane&15, row=(lane>>4)*4+reg.

typedef __attribute__((ext_vector_type(8))) short short8;
typedef __attribute__((ext_vector_type(4))) float floatx4;
typedef __attribute__((ext_vector_type(2))) float floatx2;

__device__ __forceinline__ float ex2(float x){ return __builtin_amdgcn_exp2f(x); }
__device__ __forceinline__ float rcp_(float x){ return __builtin_amdgcn_rcpf(x); }
__device__ __forceinline__ float sigm(float x){ return rcp_(1.0f + ex2(-1.44269504f*x)); }
__device__ __forceinline__ unsigned bfbits(float f){       // RNE f32->bf16 (raw bits)
    unsigned u = __builtin_bit_cast(unsigned, f);
    u += 0x7FFFu + ((u >> 16) & 1u);
    return u >> 16;
}
__device__ __forceinline__ short f2bf(float f){ return (short)bfbits(f); }
// HW packed RNE f32->2xbf16 (bit-identical to bfbits for normals).
__device__ __forceinline__ unsigned cvtpk(float lo, float hi){
    unsigned r;
    asm("v_cvt_pk_bf16_f32 %0, %1, %2" : "=v"(r) : "v"(lo), "v"(hi));
    return r;
}
// Workgroup barrier WITHOUT vmcnt drain: LDS ordering via lgkmcnt(0) only.
__device__ __forceinline__ void wg_barrier_lds(){
    asm volatile("s_waitcnt lgkmcnt(0)\n\ts_barrier" ::: "memory");
}
__device__ __forceinline__ floatx2 pk2(float a){ return (floatx2){a, a}; }

// Gate math for the CELL PAIR (tt=0,1), packed f32x2 across cells.
// zA/zB pre-scaled (i,f,o: -LG; g: +2LG); c pre-scaled by 2*log2e.
// Trans: 10 ex2 + 2 rcp. Non-trans: ~19 packed + ~5 scalar ops.
__device__ __forceinline__ floatx2 gate_update_pair(const floatx4& zA, const floatx4& zB, floatx2& c){
    floatx2 ea = pk2(1.0f) + (floatx2){ex2(zA[0]), ex2(zB[0])};   // 1+e, gate i
    floatx2 eb = pk2(1.0f) + (floatx2){ex2(zA[1]), ex2(zB[1])};   // gate f
    floatx2 eg = pk2(1.0f) + (floatx2){ex2(zA[2]), ex2(zB[2])};   // gate g
    floatx2 eo = pk2(1.0f) + (floatx2){ex2(zA[3]), ex2(zB[3])};   // gate o
    floatx2 ab = ea * eb, gd = eg * eo;
    floatx2 abgd = ab * gd;                                       // per-cell P
    float r8 = rcp_(abgd.x * abgd.y);                             // 1/(P0*P1)
    floatx2 rc = (floatx2){ r8 * abgd.y, r8 * abgd.x };           // 1/P per cell
    floatx2 gdr = gd * rc, abr = ab * rc;                         // 1/ab, 1/gd
    floatx2 iv = eb * gdr, fv = ea * gdr;                         // sig(i), sig(f)
    floatx2 rg = eo * abr, ov = eg * abr;                         // sig(g'), sig(o)
    floatx2 gp = pk2(-5.77078016f) * rg + pk2(2.88539008f);       // 2LG*tanh(zg)
    c = fv * c + iv * gp;
    floatx2 dc = pk2(1.0f) + (floatx2){ex2(c.x), ex2(c.y)};
    float rr = rcp_(dc.x * dc.y);                                 // batched tanh rcp
    floatx2 rdc = (floatx2){ rr * dc.y, rr * dc.x };
    floatx2 th = pk2(-2.0f) * rdc + pk2(1.0f);                    // tanh(c/2LG)
    return ov * th;
}

#define MFMA_BF16 __builtin_amdgcn_mfma_f32_16x16x32_bf16

__global__ __launch_bounds__(1024, 1)
void lstm2_tz(const float* __restrict__ x,
              const float* __restrict__ W1, const float* __restrict__ U1, const float* __restrict__ b1,
              const float* __restrict__ W2, const float* __restrict__ U2, const float* __restrict__ b2,
              const float* __restrict__ Wd, const float* __restrict__ bd,
              const float* __restrict__ Wo, const float* __restrict__ bo,
              float* __restrict__ out)
{
    __shared__ __align__(16) short h1b[2][16 * 64];   // [buf][batch*64 + swz-unit]
    __shared__ __align__(16) short h2b[2][16 * 64];
    __shared__ __align__(16) short xsb[2][16 * 40];   // [buf][batch*40 + feat]
    __shared__ float psum[4][16];

    const int tid  = threadIdx.x;
    const int w    = tid >> 6;            // 0..15
    const bool isL1 = (w < 8);
    const int wv   = w & 7;               // 0..7 within group
    const int lane = tid & 63;
    const int n    = lane & 15;           // B-frag col = batch row; also A-frag m
    const int q    = lane >> 4;           // quad
    const int b0   = blockIdx.x * 16;

    const float LG = 1.44269504f;         // log2(e)

    // A-frag row mapping: within-tile row m -> (unit_local = m>>2, gate = m&3)
    const int ugl = n >> 2;
    const int gA  = n & 3;
    const float sA = (gA == 2) ? (2.0f * LG) : (-LG);

    // ---- per-lane LDS offsets (shorts), swizzle sw = n&7 on 16B chunks ----
    const int sw   = n & 7;
    const int hro0 = n * 64 + ((q ^ sw) << 3);          // h chunk q      (k 0..31)
    const int hro1 = n * 64 + (((4 + q) ^ sw) << 3);    // h chunk 4+q    (k 32..63)
    const int xro  = n * 40 + q * 8;
    // write: units wv*8+q*2+{0,1} -> chunk wv, in-chunk q*2 shorts (b32 store)
    const int hwo  = n * 64 + ((wv ^ sw) << 3) + q * 2;

    // ---- one-time: weight A-fragments + bias C vectors ----
    short8  Wa[8];
    floatx4 bC[2];
    if (isL1) {
#pragma unroll
        for (int tt = 0; tt < 2; ++tt) {
            const int un   = wv * 8 + ugl * 2 + tt;     // A-frag output unit
            const int ncol = gA * 64 + un;
#pragma unroll
            for (int j = 0; j < 8; ++j) {
                const int k = q * 8 + j;
                Wa[tt * 3 + 0][j] = f2bf(W1[k * 256 + ncol] * sA);
                Wa[tt * 3 + 1][j] = f2bf(U1[k * 256 + ncol] * sA);
                Wa[tt * 3 + 2][j] = f2bf(U1[(32 + k) * 256 + ncol] * sA);
            }
#pragma unroll
            for (int r = 0; r < 4; ++r)
                bC[tt][r] = b1[r * 64 + wv * 8 + q * 2 + tt] * ((r == 2) ? (2.0f * LG) : (-LG));
        }
    } else {
#pragma unroll
        for (int tt = 0; tt < 2; ++tt) {
            const int un   = wv * 8 + ugl * 2 + tt;
            const int ncol = gA * 64 + un;
#pragma unroll
            for (int j = 0; j < 8; ++j) {
                const int k = q * 8 + j;
                Wa[tt * 4 + 0][j] = f2bf(W2[k * 256 + ncol] * sA);
                Wa[tt * 4 + 1][j] = f2bf(W2[(32 + k) * 256 + ncol] * sA);
                Wa[tt * 4 + 2][j] = f2bf(U2[k * 256 + ncol] * sA);
                Wa[tt * 4 + 3][j] = f2bf(U2[(32 + k) * 256 + ncol] * sA);
            }
#pragma unroll
            for (int r = 0; r < 4; ++r)
                bC[tt][r] = b2[r * 64 + wv * 8 + q * 2 + tt] * ((r == 2) ? (2.0f * LG) : (-LG));
        }
    }

    // ---- zero h double-buffers ----
    {
        unsigned* p1 = (unsigned*)&h1b[0][0];
        unsigned* p2 = (unsigned*)&h2b[0][0];
        for (int i = tid; i < 1024; i += 1024) { p1[i] = 0u; p2[i] = 0u; }
    }

    // ---- x staging (tid<256 = L1 waves 0-3): 2 fp32 of row (tid>>4)/step ----
    const int xr = tid >> 4;
    const int xc = (tid & 15) * 2;
    const float* xrow = x + (size_t)(b0 + xr) * 8192 + xc;   // T*F = 8192
    floatx2 xv0;
    if (tid < 256) {
        floatx2 v = *(const floatx2*)xrow;                    // x[0]
        *(unsigned*)&xsb[0][xr * 40 + xc] = cvtpk(v.x, v.y);
        xv0 = *(const floatx2*)(xrow + 32);                   // x[1]
    }
    __syncthreads();

    floatx2 c = {0.0f, 0.0f};             // cell-pair state, pre-scaled by 2*log2e
    const floatx4 zZ = {0.0f, 0.0f, 0.0f, 0.0f};   // hoisted zero acc

    // One LSTM step at compile-time parity PAR (reads h[1-PAR], writes h[PAR]).
    // Front phase (LDS reads + MFMA) runs at prio 1; gate math at prio 0.
#define LSTM_STEP(U, PAR)                                                     \
    {                                                                         \
        const int u_ = (U);                                                   \
        if (isL1) {                                                           \
            if (u_ < 256) {                                                   \
                __builtin_amdgcn_s_setprio(1);                                \
                const short* hR = &h1b[1 - (PAR)][0];                         \
                short8 bx  = *(const short8*)&xsb[(PAR)][xro];                \
                short8 bh0 = *(const short8*)&hR[hro0];                       \
                short8 bh1 = *(const short8*)&hR[hro1];                       \
                if (tid < 256 && u_ < 255) {                                  \
                    *(unsigned*)&xsb[1 - (PAR)][xr * 40 + xc] = cvtpk(xv0.x, xv0.y); \
                    if (u_ < 254) xv0 = *(const floatx2*)(xrow + (size_t)(u_ + 2) * 32); \
                }                                                             \
                floatx4 tA0 = MFMA_BF16(Wa[0], bx,  bC[0], 0, 0, 0);          \
                floatx4 tA1 = MFMA_BF16(Wa[1], bh0, zZ,    0, 0, 0);          \
                tA1 = MFMA_BF16(Wa[2], bh1, tA1, 0, 0, 0);                    \
                floatx4 tB0 = MFMA_BF16(Wa[3], bx,  bC[1], 0, 0, 0);          \
                floatx4 tB1 = MFMA_BF16(Wa[4], bh0, zZ,    0, 0, 0);          \
                tB1 = MFMA_BF16(Wa[5], bh1, tB1, 0, 0, 0);                    \
                __builtin_amdgcn_s_setprio(0);                                \
                floatx4 zA = tA0 + tA1;                                       \
                floatx4 zB = tB0 + tB1;                                       \
                floatx2 hv = gate_update_pair(zA, zB, c);                     \
                *(unsigned*)&h1b[(PAR)][hwo] = cvtpk(hv.x, hv.y);             \
            }                                                                 \
        } else {                                                              \
            if (u_ >= 1 && u_ <= 256) {                                       \
                __builtin_amdgcn_s_setprio(1);                                \
                const short* hR = &h1b[1 - (PAR)][0];                         \
                const short* gR = &h2b[(PAR)][0];                             \
                short8 bh0 = *(const short8*)&hR[hro0];                       \
                short8 bh1 = *(const short8*)&hR[hro1];                       \
                short8 bg0 = *(const short8*)&gR[hro0];                       \
                short8 bg1 = *(const short8*)&gR[hro1];                       \
                floatx4 tA0 = MFMA_BF16(Wa[0], bh0, bC[0], 0, 0, 0);          \
                tA0 = MFMA_BF16(Wa[1], bh1, tA0, 0, 0, 0);                    \
                floatx4 tA1 = MFMA_BF16(Wa[2], bg0, zZ, 0, 0, 0);             \
                tA1 = MFMA_BF16(Wa[3], bg1, tA1, 0, 0, 0);                    \
                floatx4 tB0 = MFMA_BF16(Wa[4], bh0, bC[1], 0, 0, 0);          \
                tB0 = MFMA_BF16(Wa[5], bh1, tB0, 0, 0, 0);                    \
                floatx4 tB1 = MFMA_BF16(Wa[6], bg0, zZ, 0, 0, 0);             \
                tB1 = MFMA_BF16(Wa[7], bg1, tB1, 0, 0, 0);                    \
                __builtin_amdgcn_s_setprio(0);                                \
                floatx4 zA = tA0 + tA1;                                       \
                floatx4 zB = tB0 + tB1;                                       \
                floatx2 hv = gate_update_pair(zA, zB, c);                     \
                *(unsigned*)&h2b[1 - (PAR)][hwo] = cvtpk(hv.x, hv.y);         \
            }                                                                 \
        }                                                                     \
        wg_barrier_lds();                                                     \
    }

    // u = 0..257 (u=257 is a barrier-only pad step), static parity via x2 unroll.
    for (int uu = 0; uu < 258; uu += 2) {
        LSTM_STEP(uu,     0)
        LSTM_STEP(uu + 1, 1)
    }
#undef LSTM_STEP

    // ---- epilogue (waves 8-11): h_last = h2[255] in h2b[1] ----
    // Dense(64,sigmoid): A = h2 rows (swizzled read), B = Wd columns.
    if (!isL1 && wv < 4) {
        const int colD = wv * 16 + n;
        short8 wd0, wd1;
#pragma unroll
        for (int j = 0; j < 8; ++j) {
            wd0[j] = f2bf(Wd[(q * 8 + j) * 64 + colD] * (-LG));
            wd1[j] = f2bf(Wd[(32 + q * 8 + j) * 64 + colD] * (-LG));
        }
        short8 hA0 = *(const short8*)&h2b[1][hro0];
        short8 hA1 = *(const short8*)&h2b[1][hro1];
        const float bdv = bd[colD] * (-LG);
        floatx4 dacc = { bdv, bdv, bdv, bdv };
        dacc = MFMA_BF16(hA0, wd0, dacc, 0, 0, 0);
        dacc = MFMA_BF16(hA1, wd1, dacc, 0, 0, 0);
        const float wo = Wo[colD];
#pragma unroll
        for (int r = 0; r < 4; ++r) {
            float p = rcp_(1.0f + ex2(dacc[r])) * wo;   // sigm (scale folded)
            p += __shfl_xor(p, 1, 64);
            p += __shfl_xor(p, 2, 64);
            p += __shfl_xor(p, 4, 64);
            p += __shfl_xor(p, 8, 64);                  // sum over 16 dense units
            if (n == 0) psum[wv][q * 4 + r] = p;
        }
    }
    __syncthreads();
    if (tid < 16) {
        float s = psum[0][tid] + psum[1][tid] + psum[2][tid] + psum[3][tid] + bo[0];
        out[b0 + tid] = sigm(s);
    }
}

extern "C" void kernel_launch(void* const* d_in, const int* in_sizes, int n_in,
                              void* d_out, int out_size, void* d_ws, size_t ws_size,
                              hipStream_t stream) {
    (void)in_sizes; (void)n_in; (void)d_ws; (void)ws_size; (void)out_size;
    const float* x  = (const float*)d_in[0];
    const float* W1 = (const float*)d_in[1];
    const float* U1 = (const float*)d_in[2];
    const float* b1 = (const float*)d_in[3];
    const float* W2 = (const float*)d_in[4];
    const float* U2 = (const float*)d_in[5];
    const float* b2 = (const float*)d_in[6];
    const float* Wd = (const float*)d_in[7];
    const float* bd = (const float*)d_in[8];
    const float* Wo = (const float*)d_in[9];
    const float* bo = (const float*)d_in[10];
    lstm2_tz<<<dim3(256), dim3(1024), 0, stream>>>(
        x, W1, U1, b1, W2, U2, b2, Wd, bd, Wo, bo, (float*)d_out);
}

// Round 8
// 349.021 us; speedup vs baseline: 1.0025x; 1.0025x over previous
//
#include <hip/hip_runtime.h>

// Fused 2-layer LSTM (H=64) + Dense(64,sigmoid) + Dense(1,sigmoid), MFMA bf16.
// Transposed-z formulation: z^T[gate-unit, batch] = Wt @ [x|h]^T.
// B=4096, T=256, F=32. One WG = 1024 threads = 16 waves handles BB=16 rows.
// Waves 0-7 (L1): layer 1 step u, 2 M-tiles each; waves 8-15 (L2): layer 2
// step u-1, 2 M-tiles each. One barrier per step; double-buffered h1/h2/x.
//
// R8 = R6 + SPLIT MFMA TREES ONLY (R7's setprio removed -- it starved the
// critical gate chain: prioritizing the front phase deprioritized the
// serial tail into the barrier, +31us. Counters: VALUBusy 52.5->49.4,
// MfmaUtil 26->22.8 with LONGER steps = priority starvation, not overlap).
//  - SPLIT MFMA TREES: z = (A0 x + bias) || (A1 h0 + A2 h1) as two parallel
//    accumulators merged by v_pk_add_f32 -> dep depth 3-4 MFMA -> 2 + add.
// Retained from R5/R6 (verified): packed-f32 gate pair math, batched rcp
// (10 ex2 + 2 rcp / wave-step), x2-unrolled static parity, lgkm-only
// barrier (no vmcnt drain), XOR-swizzled conflict-free h layout, b32
// cvt_pk h-writes, activation scales folded into weights, bias via MFMA C.
// MFMA 16x16x32 layouts (learn_hip-verified):
//   A[m=lane&15][k=(lane>>4)*8+j], B[k=(lane>>4)*8+j][n=lane&15],
//   C/D: col=lane&15, row=(lane>>4)*4+reg.

typedef __attribute__((ext_vector_type(8))) short short8;
typedef __attribute__((ext_vector_type(4))) float floatx4;
typedef __attribute__((ext_vector_type(2))) float floatx2;

__device__ __forceinline__ float ex2(float x){ return __builtin_amdgcn_exp2f(x); }
__device__ __forceinline__ float rcp_(float x){ return __builtin_amdgcn_rcpf(x); }
__device__ __forceinline__ float sigm(float x){ return rcp_(1.0f + ex2(-1.44269504f*x)); }
__device__ __forceinline__ unsigned bfbits(float f){       // RNE f32->bf16 (raw bits)
    unsigned u = __builtin_bit_cast(unsigned, f);
    u += 0x7FFFu + ((u >> 16) & 1u);
    return u >> 16;
}
__device__ __forceinline__ short f2bf(float f){ return (short)bfbits(f); }
// HW packed RNE f32->2xbf16 (bit-identical to bfbits for normals).
__device__ __forceinline__ unsigned cvtpk(float lo, float hi){
    unsigned r;
    asm("v_cvt_pk_bf16_f32 %0, %1, %2" : "=v"(r) : "v"(lo), "v"(hi));
    return r;
}
// Workgroup barrier WITHOUT vmcnt drain: LDS ordering via lgkmcnt(0) only.
__device__ __forceinline__ void wg_barrier_lds(){
    asm volatile("s_waitcnt lgkmcnt(0)\n\ts_barrier" ::: "memory");
}
__device__ __forceinline__ floatx2 pk2(float a){ return (floatx2){a, a}; }

// Gate math for the CELL PAIR (tt=0,1), packed f32x2 across cells.
// zA/zB pre-scaled (i,f,o: -LG; g: +2LG); c pre-scaled by 2*log2e.
// Trans: 10 ex2 + 2 rcp. Non-trans: ~19 packed + ~5 scalar ops.
__device__ __forceinline__ floatx2 gate_update_pair(const floatx4& zA, const floatx4& zB, floatx2& c){
    floatx2 ea = pk2(1.0f) + (floatx2){ex2(zA[0]), ex2(zB[0])};   // 1+e, gate i
    floatx2 eb = pk2(1.0f) + (floatx2){ex2(zA[1]), ex2(zB[1])};   // gate f
    floatx2 eg = pk2(1.0f) + (floatx2){ex2(zA[2]), ex2(zB[2])};   // gate g
    floatx2 eo = pk2(1.0f) + (floatx2){ex2(zA[3]), ex2(zB[3])};   // gate o
    floatx2 ab = ea * eb, gd = eg * eo;
    floatx2 abgd = ab * gd;                                       // per-cell P
    float r8 = rcp_(abgd.x * abgd.y);                             // 1/(P0*P1)
    floatx2 rc = (floatx2){ r8 * abgd.y, r8 * abgd.x };           // 1/P per cell
    floatx2 gdr = gd * rc, abr = ab * rc;                         // 1/ab, 1/gd
    floatx2 iv = eb * gdr, fv = ea * gdr;                         // sig(i), sig(f)
    floatx2 rg = eo * abr, ov = eg * abr;                         // sig(g'), sig(o)
    floatx2 gp = pk2(-5.77078016f) * rg + pk2(2.88539008f);       // 2LG*tanh(zg)
    c = fv * c + iv * gp;
    floatx2 dc = pk2(1.0f) + (floatx2){ex2(c.x), ex2(c.y)};
    float rr = rcp_(dc.x * dc.y);                                 // batched tanh rcp
    floatx2 rdc = (floatx2){ rr * dc.y, rr * dc.x };
    floatx2 th = pk2(-2.0f) * rdc + pk2(1.0f);                    // tanh(c/2LG)
    return ov * th;
}

#define MFMA_BF16 __builtin_amdgcn_mfma_f32_16x16x32_bf16

__global__ __launch_bounds__(1024, 1)
void lstm2_tz(const float* __restrict__ x,
              const float* __restrict__ W1, const float* __restrict__ U1, const float* __restrict__ b1,
              const float* __restrict__ W2, const float* __restrict__ U2, const float* __restrict__ b2,
              const float* __restrict__ Wd, const float* __restrict__ bd,
              const float* __restrict__ Wo, const float* __restrict__ bo,
              float* __restrict__ out)
{
    __shared__ __align__(16) short h1b[2][16 * 64];   // [buf][batch*64 + swz-unit]
    __shared__ __align__(16) short h2b[2][16 * 64];
    __shared__ __align__(16) short xsb[2][16 * 40];   // [buf][batch*40 + feat]
    __shared__ float psum[4][16];

    const int tid  = threadIdx.x;
    const int w    = tid >> 6;            // 0..15
    const bool isL1 = (w < 8);
    const int wv   = w & 7;               // 0..7 within group
    const int lane = tid & 63;
    const int n    = lane & 15;           // B-frag col = batch row; also A-frag m
    const int q    = lane >> 4;           // quad
    const int b0   = blockIdx.x * 16;

    const float LG = 1.44269504f;         // log2(e)

    // A-frag row mapping: within-tile row m -> (unit_local = m>>2, gate = m&3)
    const int ugl = n >> 2;
    const int gA  = n & 3;
    const float sA = (gA == 2) ? (2.0f * LG) : (-LG);

    // ---- per-lane LDS offsets (shorts), swizzle sw = n&7 on 16B chunks ----
    const int sw   = n & 7;
    const int hro0 = n * 64 + ((q ^ sw) << 3);          // h chunk q      (k 0..31)
    const int hro1 = n * 64 + (((4 + q) ^ sw) << 3);    // h chunk 4+q    (k 32..63)
    const int xro  = n * 40 + q * 8;
    // write: units wv*8+q*2+{0,1} -> chunk wv, in-chunk q*2 shorts (b32 store)
    const int hwo  = n * 64 + ((wv ^ sw) << 3) + q * 2;

    // ---- one-time: weight A-fragments + bias C vectors ----
    short8  Wa[8];
    floatx4 bC[2];
    if (isL1) {
#pragma unroll
        for (int tt = 0; tt < 2; ++tt) {
            const int un   = wv * 8 + ugl * 2 + tt;     // A-frag output unit
            const int ncol = gA * 64 + un;
#pragma unroll
            for (int j = 0; j < 8; ++j) {
                const int k = q * 8 + j;
                Wa[tt * 3 + 0][j] = f2bf(W1[k * 256 + ncol] * sA);
                Wa[tt * 3 + 1][j] = f2bf(U1[k * 256 + ncol] * sA);
                Wa[tt * 3 + 2][j] = f2bf(U1[(32 + k) * 256 + ncol] * sA);
            }
#pragma unroll
            for (int r = 0; r < 4; ++r)
                bC[tt][r] = b1[r * 64 + wv * 8 + q * 2 + tt] * ((r == 2) ? (2.0f * LG) : (-LG));
        }
    } else {
#pragma unroll
        for (int tt = 0; tt < 2; ++tt) {
            const int un   = wv * 8 + ugl * 2 + tt;
            const int ncol = gA * 64 + un;
#pragma unroll
            for (int j = 0; j < 8; ++j) {
                const int k = q * 8 + j;
                Wa[tt * 4 + 0][j] = f2bf(W2[k * 256 + ncol] * sA);
                Wa[tt * 4 + 1][j] = f2bf(W2[(32 + k) * 256 + ncol] * sA);
                Wa[tt * 4 + 2][j] = f2bf(U2[k * 256 + ncol] * sA);
                Wa[tt * 4 + 3][j] = f2bf(U2[(32 + k) * 256 + ncol] * sA);
            }
#pragma unroll
            for (int r = 0; r < 4; ++r)
                bC[tt][r] = b2[r * 64 + wv * 8 + q * 2 + tt] * ((r == 2) ? (2.0f * LG) : (-LG));
        }
    }

    // ---- zero h double-buffers ----
    {
        unsigned* p1 = (unsigned*)&h1b[0][0];
        unsigned* p2 = (unsigned*)&h2b[0][0];
        for (int i = tid; i < 1024; i += 1024) { p1[i] = 0u; p2[i] = 0u; }
    }

    // ---- x staging (tid<256 = L1 waves 0-3): 2 fp32 of row (tid>>4)/step ----
    const int xr = tid >> 4;
    const int xc = (tid & 15) * 2;
    const float* xrow = x + (size_t)(b0 + xr) * 8192 + xc;   // T*F = 8192
    floatx2 xv0;
    if (tid < 256) {
        floatx2 v = *(const floatx2*)xrow;                    // x[0]
        *(unsigned*)&xsb[0][xr * 40 + xc] = cvtpk(v.x, v.y);
        xv0 = *(const floatx2*)(xrow + 32);                   // x[1]
    }
    __syncthreads();

    floatx2 c = {0.0f, 0.0f};             // cell-pair state, pre-scaled by 2*log2e
    const floatx4 zZ = {0.0f, 0.0f, 0.0f, 0.0f};   // hoisted zero acc

    // One LSTM step at compile-time parity PAR (reads h[1-PAR], writes h[PAR]).
#define LSTM_STEP(U, PAR)                                                     \
    {                                                                         \
        const int u_ = (U);                                                   \
        if (isL1) {                                                           \
            if (u_ < 256) {                                                   \
                const short* hR = &h1b[1 - (PAR)][0];                         \
                short8 bx  = *(const short8*)&xsb[(PAR)][xro];                \
                short8 bh0 = *(const short8*)&hR[hro0];                       \
                short8 bh1 = *(const short8*)&hR[hro1];                       \
                if (tid < 256 && u_ < 255) {                                  \
                    *(unsigned*)&xsb[1 - (PAR)][xr * 40 + xc] = cvtpk(xv0.x, xv0.y); \
                    if (u_ < 254) xv0 = *(const floatx2*)(xrow + (size_t)(u_ + 2) * 32); \
                }                                                             \
                floatx4 tA0 = MFMA_BF16(Wa[0], bx,  bC[0], 0, 0, 0);          \
                floatx4 tA1 = MFMA_BF16(Wa[1], bh0, zZ,    0, 0, 0);          \
                tA1 = MFMA_BF16(Wa[2], bh1, tA1, 0, 0, 0);                    \
                floatx4 tB0 = MFMA_BF16(Wa[3], bx,  bC[1], 0, 0, 0);          \
                floatx4 tB1 = MFMA_BF16(Wa[4], bh0, zZ,    0, 0, 0);          \
                tB1 = MFMA_BF16(Wa[5], bh1, tB1, 0, 0, 0);                    \
                floatx4 zA = tA0 + tA1;                                       \
                floatx4 zB = tB0 + tB1;                                       \
                floatx2 hv = gate_update_pair(zA, zB, c);                     \
                *(unsigned*)&h1b[(PAR)][hwo] = cvtpk(hv.x, hv.y);             \
            }                                                                 \
        } else {                                                              \
            if (u_ >= 1 && u_ <= 256) {                                       \
                const short* hR = &h1b[1 - (PAR)][0];                         \
                const short* gR = &h2b[(PAR)][0];                             \
                short8 bh0 = *(const short8*)&hR[hro0];                       \
                short8 bh1 = *(const short8*)&hR[hro1];                       \
                short8 bg0 = *(const short8*)&gR[hro0];                       \
                short8 bg1 = *(const short8*)&gR[hro1];                       \
                floatx4 tA0 = MFMA_BF16(Wa[0], bh0, bC[0], 0, 0, 0);          \
                tA0 = MFMA_BF16(Wa[1], bh1, tA0, 0, 0, 0);                    \
                floatx4 tA1 = MFMA_BF16(Wa[2], bg0, zZ, 0, 0, 0);             \
                tA1 = MFMA_BF16(Wa[3], bg1, tA1, 0, 0, 0);                    \
                floatx4 tB0 = MFMA_BF16(Wa[4], bh0, bC[1], 0, 0, 0);          \
                tB0 = MFMA_BF16(Wa[5], bh1, tB0, 0, 0, 0);                    \
                floatx4 tB1 = MFMA_BF16(Wa[6], bg0, zZ, 0, 0, 0);             \
                tB1 = MFMA_BF16(Wa[7], bg1, tB1, 0, 0, 0);                    \
                floatx4 zA = tA0 + tA1;                                       \
                floatx4 zB = tB0 + tB1;                                       \
                floatx2 hv = gate_update_pair(zA, zB, c);                     \
                *(unsigned*)&h2b[1 - (PAR)][hwo] = cvtpk(hv.x, hv.y);         \
            }                                                                 \
        }                                                                     \
        wg_barrier_lds();                                                     \
    }

    // u = 0..257 (u=257 is a barrier-only pad step), static parity via x2 unroll.
    for (int uu = 0; uu < 258; uu += 2) {
        LSTM_STEP(uu,     0)
        LSTM_STEP(uu + 1, 1)
    }
#undef LSTM_STEP

    // ---- epilogue (waves 8-11): h_last = h2[255] in h2b[1] ----
    // Dense(64,sigmoid): A = h2 rows (swizzled read), B = Wd columns.
    if (!isL1 && wv < 4) {
        const int colD = wv * 16 + n;
        short8 wd0, wd1;
#pragma unroll
        for (int j = 0; j < 8; ++j) {
            wd0[j] = f2bf(Wd[(q * 8 + j) * 64 + colD] * (-LG));
            wd1[j] = f2bf(Wd[(32 + q * 8 + j) * 64 + colD] * (-LG));
        }
        short8 hA0 = *(const short8*)&h2b[1][hro0];
        short8 hA1 = *(const short8*)&h2b[1][hro1];
        const float bdv = bd[colD] * (-LG);
        floatx4 dacc = { bdv, bdv, bdv, bdv };
        dacc = MFMA_BF16(hA0, wd0, dacc, 0, 0, 0);
        dacc = MFMA_BF16(hA1, wd1, dacc, 0, 0, 0);
        const float wo = Wo[colD];
#pragma unroll
        for (int r = 0; r < 4; ++r) {
            float p = rcp_(1.0f + ex2(dacc[r])) * wo;   // sigm (scale folded)
            p += __shfl_xor(p, 1, 64);
            p += __shfl_xor(p, 2, 64);
            p += __shfl_xor(p, 4, 64);
            p += __shfl_xor(p, 8, 64);                  // sum over 16 dense units
            if (n == 0) psum[wv][q * 4 + r] = p;
        }
    }
    __syncthreads();
    if (tid < 16) {
        float s = psum[0][tid] + psum[1][tid] + psum[2][tid] + psum[3][tid] + bo[0];
        out[b0 + tid] = sigm(s);
    }
}

extern "C" void kernel_launch(void* const* d_in, const int* in_sizes, int n_in,
                              void* d_out, int out_size, void* d_ws, size_t ws_size,
                              hipStream_t stream) {
    (void)in_sizes; (void)n_in; (void)d_ws; (void)ws_size; (void)out_size;
    const float* x  = (const float*)d_in[0];
    const float* W1 = (const float*)d_in[1];
    const float* U1 = (const float*)d_in[2];
    const float* b1 = (const float*)d_in[3];
    const float* W2 = (const float*)d_in[4];
    const float* U2 = (const float*)d_in[5];
    const float* b2 = (const float*)d_in[6];
    const float* Wd = (const float*)d_in[7];
    const float* bd = (const float*)d_in[8];
    const float* Wo = (const float*)d_in[9];
    const float* bo = (const float*)d_in[10];
    lstm2_tz<<<dim3(256), dim3(1024), 0, stream>>>(
        x, W1, U1, b1, W2, U2, b2, Wd, bd, Wo, bo, (float*)d_out);
}

// Round 9
// 327.386 us; speedup vs baseline: 1.0688x; 1.0661x over previous
//
#include <hip/hip_runtime.h>

// Fused 2-layer LSTM (H=64) + Dense(64,sigmoid) + Dense(1,sigmoid), MFMA bf16.
// Transposed-z formulation: z^T[gate-unit, batch] = Wt @ [x|h]^T.
// B=4096, T=256, F=32. One WG = 1024 threads = 16 waves handles BB=16 rows.
// Waves 0-7 (L1): layer 1 step u, 2 M-tiles each; waves 8-15 (L2): layer 2
// step u-1, 2 M-tiles each. One barrier per step; double-buffered h1/h2/x.
//
// R9 = EXACT REVERT TO R6 (best: 202us profiled). R7/R8 established:
//  - setprio(1) on front phase: REGRESSION (+8us) -- starves the critical
//    gate chain into the barrier.
//  - split MFMA accumulator trees: REGRESSION (+23us) -- C-operand chaining
//    is free in the MFMA pipe; the split's merge adds + acc-init movs land
//    on the VALU issue port, which is the binding resource.
// Verified-win inventory (all retained): packed-f32 gate pair math +
// batched rcp (10 ex2 + 2 rcp / wave-step) [R6 -2%], x2-unrolled static
// parity + batched rcp [R5 -9%], lgkm-only barrier (no vmcnt drain),
// XOR-swizzled conflict-free h layout (chunk' = chunk ^ (batch&7)),
// b32 cvt_pk h-writes, activation scales folded into weights
// (i,f,o: -log2e; g: +2*log2e), cell state pre-scaled by 2*log2e,
// bias via MFMA C operand.
// MFMA 16x16x32 layouts (learn_hip-verified):
//   A[m=lane&15][k=(lane>>4)*8+j], B[k=(lane>>4)*8+j][n=lane&15],
//   C/D: col=lane&15, row=(lane>>4)*4+reg.

typedef __attribute__((ext_vector_type(8))) short short8;
typedef __attribute__((ext_vector_type(4))) float floatx4;
typedef __attribute__((ext_vector_type(2))) float floatx2;

__device__ __forceinline__ float ex2(float x){ return __builtin_amdgcn_exp2f(x); }
__device__ __forceinline__ float rcp_(float x){ return __builtin_amdgcn_rcpf(x); }
__device__ __forceinline__ float sigm(float x){ return rcp_(1.0f + ex2(-1.44269504f*x)); }
__device__ __forceinline__ unsigned bfbits(float f){       // RNE f32->bf16 (raw bits)
    unsigned u = __builtin_bit_cast(unsigned, f);
    u += 0x7FFFu + ((u >> 16) & 1u);
    return u >> 16;
}
__device__ __forceinline__ short f2bf(float f){ return (short)bfbits(f); }
// HW packed RNE f32->2xbf16 (bit-identical to bfbits for normals).
__device__ __forceinline__ unsigned cvtpk(float lo, float hi){
    unsigned r;
    asm("v_cvt_pk_bf16_f32 %0, %1, %2" : "=v"(r) : "v"(lo), "v"(hi));
    return r;
}
// Workgroup barrier WITHOUT vmcnt drain: LDS ordering via lgkmcnt(0) only.
__device__ __forceinline__ void wg_barrier_lds(){
    asm volatile("s_waitcnt lgkmcnt(0)\n\ts_barrier" ::: "memory");
}
__device__ __forceinline__ floatx2 pk2(float a){ return (floatx2){a, a}; }

// Gate math for the CELL PAIR (tt=0,1), packed f32x2 across cells.
// zA/zB pre-scaled (i,f,o: -LG; g: +2LG); c pre-scaled by 2*log2e.
// Trans: 10 ex2 + 2 rcp. Non-trans: ~19 packed + ~5 scalar ops.
__device__ __forceinline__ floatx2 gate_update_pair(const floatx4& zA, const floatx4& zB, floatx2& c){
    floatx2 ea = pk2(1.0f) + (floatx2){ex2(zA[0]), ex2(zB[0])};   // 1+e, gate i
    floatx2 eb = pk2(1.0f) + (floatx2){ex2(zA[1]), ex2(zB[1])};   // gate f
    floatx2 eg = pk2(1.0f) + (floatx2){ex2(zA[2]), ex2(zB[2])};   // gate g
    floatx2 eo = pk2(1.0f) + (floatx2){ex2(zA[3]), ex2(zB[3])};   // gate o
    floatx2 ab = ea * eb, gd = eg * eo;
    floatx2 abgd = ab * gd;                                       // per-cell P
    float r8 = rcp_(abgd.x * abgd.y);                             // 1/(P0*P1)
    floatx2 rc = (floatx2){ r8 * abgd.y, r8 * abgd.x };           // 1/P per cell
    floatx2 gdr = gd * rc, abr = ab * rc;                         // 1/ab, 1/gd
    floatx2 iv = eb * gdr, fv = ea * gdr;                         // sig(i), sig(f)
    floatx2 rg = eo * abr, ov = eg * abr;                         // sig(g'), sig(o)
    floatx2 gp = pk2(-5.77078016f) * rg + pk2(2.88539008f);       // 2LG*tanh(zg)
    c = fv * c + iv * gp;
    floatx2 dc = pk2(1.0f) + (floatx2){ex2(c.x), ex2(c.y)};
    float rr = rcp_(dc.x * dc.y);                                 // batched tanh rcp
    floatx2 rdc = (floatx2){ rr * dc.y, rr * dc.x };
    floatx2 th = pk2(-2.0f) * rdc + pk2(1.0f);                    // tanh(c/2LG)
    return ov * th;
}

#define MFMA_BF16 __builtin_amdgcn_mfma_f32_16x16x32_bf16

__global__ __launch_bounds__(1024, 1)
void lstm2_tz(const float* __restrict__ x,
              const float* __restrict__ W1, const float* __restrict__ U1, const float* __restrict__ b1,
              const float* __restrict__ W2, const float* __restrict__ U2, const float* __restrict__ b2,
              const float* __restrict__ Wd, const float* __restrict__ bd,
              const float* __restrict__ Wo, const float* __restrict__ bo,
              float* __restrict__ out)
{
    __shared__ __align__(16) short h1b[2][16 * 64];   // [buf][batch*64 + swz-unit]
    __shared__ __align__(16) short h2b[2][16 * 64];
    __shared__ __align__(16) short xsb[2][16 * 40];   // [buf][batch*40 + feat]
    __shared__ float psum[4][16];

    const int tid  = threadIdx.x;
    const int w    = tid >> 6;            // 0..15
    const bool isL1 = (w < 8);
    const int wv   = w & 7;               // 0..7 within group
    const int lane = tid & 63;
    const int n    = lane & 15;           // B-frag col = batch row; also A-frag m
    const int q    = lane >> 4;           // quad
    const int b0   = blockIdx.x * 16;

    const float LG = 1.44269504f;         // log2(e)

    // A-frag row mapping: within-tile row m -> (unit_local = m>>2, gate = m&3)
    const int ugl = n >> 2;
    const int gA  = n & 3;
    const float sA = (gA == 2) ? (2.0f * LG) : (-LG);

    // ---- per-lane LDS offsets (shorts), swizzle sw = n&7 on 16B chunks ----
    const int sw   = n & 7;
    const int hro0 = n * 64 + ((q ^ sw) << 3);          // h chunk q      (k 0..31)
    const int hro1 = n * 64 + (((4 + q) ^ sw) << 3);    // h chunk 4+q    (k 32..63)
    const int xro  = n * 40 + q * 8;
    // write: units wv*8+q*2+{0,1} -> chunk wv, in-chunk q*2 shorts (b32 store)
    const int hwo  = n * 64 + ((wv ^ sw) << 3) + q * 2;

    // ---- one-time: weight A-fragments + bias C vectors ----
    short8  Wa[8];
    floatx4 bC[2];
    if (isL1) {
#pragma unroll
        for (int tt = 0; tt < 2; ++tt) {
            const int un   = wv * 8 + ugl * 2 + tt;     // A-frag output unit
            const int ncol = gA * 64 + un;
#pragma unroll
            for (int j = 0; j < 8; ++j) {
                const int k = q * 8 + j;
                Wa[tt * 3 + 0][j] = f2bf(W1[k * 256 + ncol] * sA);
                Wa[tt * 3 + 1][j] = f2bf(U1[k * 256 + ncol] * sA);
                Wa[tt * 3 + 2][j] = f2bf(U1[(32 + k) * 256 + ncol] * sA);
            }
#pragma unroll
            for (int r = 0; r < 4; ++r)
                bC[tt][r] = b1[r * 64 + wv * 8 + q * 2 + tt] * ((r == 2) ? (2.0f * LG) : (-LG));
        }
    } else {
#pragma unroll
        for (int tt = 0; tt < 2; ++tt) {
            const int un   = wv * 8 + ugl * 2 + tt;
            const int ncol = gA * 64 + un;
#pragma unroll
            for (int j = 0; j < 8; ++j) {
                const int k = q * 8 + j;
                Wa[tt * 4 + 0][j] = f2bf(W2[k * 256 + ncol] * sA);
                Wa[tt * 4 + 1][j] = f2bf(W2[(32 + k) * 256 + ncol] * sA);
                Wa[tt * 4 + 2][j] = f2bf(U2[k * 256 + ncol] * sA);
                Wa[tt * 4 + 3][j] = f2bf(U2[(32 + k) * 256 + ncol] * sA);
            }
#pragma unroll
            for (int r = 0; r < 4; ++r)
                bC[tt][r] = b2[r * 64 + wv * 8 + q * 2 + tt] * ((r == 2) ? (2.0f * LG) : (-LG));
        }
    }

    // ---- zero h double-buffers ----
    {
        unsigned* p1 = (unsigned*)&h1b[0][0];
        unsigned* p2 = (unsigned*)&h2b[0][0];
        for (int i = tid; i < 1024; i += 1024) { p1[i] = 0u; p2[i] = 0u; }
    }

    // ---- x staging (tid<256 = L1 waves 0-3): 2 fp32 of row (tid>>4)/step ----
    const int xr = tid >> 4;
    const int xc = (tid & 15) * 2;
    const float* xrow = x + (size_t)(b0 + xr) * 8192 + xc;   // T*F = 8192
    floatx2 xv0;
    if (tid < 256) {
        floatx2 v = *(const floatx2*)xrow;                    // x[0]
        *(unsigned*)&xsb[0][xr * 40 + xc] = cvtpk(v.x, v.y);
        xv0 = *(const floatx2*)(xrow + 32);                   // x[1]
    }
    __syncthreads();

    floatx2 c = {0.0f, 0.0f};             // cell-pair state, pre-scaled by 2*log2e

    // One LSTM step at compile-time parity PAR (reads h[1-PAR], writes h[PAR]).
#define LSTM_STEP(U, PAR)                                                     \
    {                                                                         \
        const int u_ = (U);                                                   \
        if (isL1) {                                                           \
            if (u_ < 256) {                                                   \
                const short* hR = &h1b[1 - (PAR)][0];                         \
                short8 bx  = *(const short8*)&xsb[(PAR)][xro];                \
                short8 bh0 = *(const short8*)&hR[hro0];                       \
                short8 bh1 = *(const short8*)&hR[hro1];                       \
                if (tid < 256 && u_ < 255) {                                  \
                    *(unsigned*)&xsb[1 - (PAR)][xr * 40 + xc] = cvtpk(xv0.x, xv0.y); \
                    if (u_ < 254) xv0 = *(const floatx2*)(xrow + (size_t)(u_ + 2) * 32); \
                }                                                             \
                floatx4 zA = bC[0];                                           \
                zA = MFMA_BF16(Wa[0], bx,  zA, 0, 0, 0);                      \
                zA = MFMA_BF16(Wa[1], bh0, zA, 0, 0, 0);                      \
                zA = MFMA_BF16(Wa[2], bh1, zA, 0, 0, 0);                      \
                floatx4 zB = bC[1];                                           \
                zB = MFMA_BF16(Wa[3], bx,  zB, 0, 0, 0);                      \
                zB = MFMA_BF16(Wa[4], bh0, zB, 0, 0, 0);                      \
                zB = MFMA_BF16(Wa[5], bh1, zB, 0, 0, 0);                      \
                floatx2 hv = gate_update_pair(zA, zB, c);                     \
                *(unsigned*)&h1b[(PAR)][hwo] = cvtpk(hv.x, hv.y);             \
            }                                                                 \
        } else {                                                              \
            if (u_ >= 1 && u_ <= 256) {                                       \
                const short* hR = &h1b[1 - (PAR)][0];                         \
                const short* gR = &h2b[(PAR)][0];                             \
                short8 bh0 = *(const short8*)&hR[hro0];                       \
                short8 bh1 = *(const short8*)&hR[hro1];                       \
                short8 bg0 = *(const short8*)&gR[hro0];                       \
                short8 bg1 = *(const short8*)&gR[hro1];                       \
                floatx4 zA = bC[0];                                           \
                zA = MFMA_BF16(Wa[0], bh0, zA, 0, 0, 0);                      \
                zA = MFMA_BF16(Wa[1], bh1, zA, 0, 0, 0);                      \
                zA = MFMA_BF16(Wa[2], bg0, zA, 0, 0, 0);                      \
                zA = MFMA_BF16(Wa[3], bg1, zA, 0, 0, 0);                      \
                floatx4 zB = bC[1];                                           \
                zB = MFMA_BF16(Wa[4], bh0, zB, 0, 0, 0);                      \
                zB = MFMA_BF16(Wa[5], bh1, zB, 0, 0, 0);                      \
                zB = MFMA_BF16(Wa[6], bg0, zB, 0, 0, 0);                      \
                zB = MFMA_BF16(Wa[7], bg1, zB, 0, 0, 0);                      \
                floatx2 hv = gate_update_pair(zA, zB, c);                     \
                *(unsigned*)&h2b[1 - (PAR)][hwo] = cvtpk(hv.x, hv.y);         \
            }                                                                 \
        }                                                                     \
        wg_barrier_lds();                                                     \
    }

    // u = 0..257 (u=257 is a barrier-only pad step), static parity via x2 unroll.
    for (int uu = 0; uu < 258; uu += 2) {
        LSTM_STEP(uu,     0)
        LSTM_STEP(uu + 1, 1)
    }
#undef LSTM_STEP

    // ---- epilogue (waves 8-11): h_last = h2[255] in h2b[1] ----
    // Dense(64,sigmoid): A = h2 rows (swizzled read), B = Wd columns.
    if (!isL1 && wv < 4) {
        const int colD = wv * 16 + n;
        short8 wd0, wd1;
#pragma unroll
        for (int j = 0; j < 8; ++j) {
            wd0[j] = f2bf(Wd[(q * 8 + j) * 64 + colD] * (-LG));
            wd1[j] = f2bf(Wd[(32 + q * 8 + j) * 64 + colD] * (-LG));
        }
        short8 hA0 = *(const short8*)&h2b[1][hro0];
        short8 hA1 = *(const short8*)&h2b[1][hro1];
        const float bdv = bd[colD] * (-LG);
        floatx4 dacc = { bdv, bdv, bdv, bdv };
        dacc = MFMA_BF16(hA0, wd0, dacc, 0, 0, 0);
        dacc = MFMA_BF16(hA1, wd1, dacc, 0, 0, 0);
        const float wo = Wo[colD];
#pragma unroll
        for (int r = 0; r < 4; ++r) {
            float p = rcp_(1.0f + ex2(dacc[r])) * wo;   // sigm (scale folded)
            p += __shfl_xor(p, 1, 64);
            p += __shfl_xor(p, 2, 64);
            p += __shfl_xor(p, 4, 64);
            p += __shfl_xor(p, 8, 64);                  // sum over 16 dense units
            if (n == 0) psum[wv][q * 4 + r] = p;
        }
    }
    __syncthreads();
    if (tid < 16) {
        float s = psum[0][tid] + psum[1][tid] + psum[2][tid] + psum[3][tid] + bo[0];
        out[b0 + tid] = sigm(s);
    }
}

extern "C" void kernel_launch(void* const* d_in, const int* in_sizes, int n_in,
                              void* d_out, int out_size, void* d_ws, size_t ws_size,
                              hipStream_t stream) {
    (void)in_sizes; (void)n_in; (void)d_ws; (void)ws_size; (void)out_size;
    const float* x  = (const float*)d_in[0];
    const float* W1 = (const float*)d_in[1];
    const float* U1 = (const float*)d_in[2];
    const float* b1 = (const float*)d_in[3];
    const float* W2 = (const float*)d_in[4];
    const float* U2 = (const float*)d_in[5];
    const float* b2 = (const float*)d_in[6];
    const float* Wd = (const float*)d_in[7];
    const float* bd = (const float*)d_in[8];
    const float* Wo = (const float*)d_in[9];
    const float* bo = (const float*)d_in[10];
    lstm2_tz<<<dim3(256), dim3(1024), 0, stream>>>(
        x, W1, U1, b1, W2, U2, b2, Wd, bd, Wo, bo, (float*)d_out);
}